// Round 6
// baseline (95.010 us; speedup 1.0000x reference)
//
#include <hip/hip_runtime.h>
#include <stdint.h>

#define IN_F 2048
#define OUT_F 2048
#define N_ROWS 8192

// ---- GEMM geometry: 256x256 tile, BK=64, 8 waves (2Mx4N), 8-phase schedule
#define BM 256
#define BN 256
#define BK 64
#define NT (IN_F / BK)             // 32 K-steps
#define TM_TILES (N_ROWS / BM)     // 32
#define TN_TILES (OUT_F / BN)      // 8
#define NWG (TM_TILES * TN_TILES)  // 256 == #CUs
// LDS: parity P in {0,1}: A at P*32768, B at P*32768+16384 (shorts). 128 KiB.
#define AB_STRIDE 32768
#define B_OFF 16384

typedef __bf16 bf16x8 __attribute__((ext_vector_type(8)));
typedef float f32x4 __attribute__((ext_vector_type(4)));
typedef unsigned short ushortx8 __attribute__((ext_vector_type(8)));

__device__ __forceinline__ unsigned short f2bf(float f) {
  unsigned u = __builtin_bit_cast(unsigned, f);
  u += 0x7FFFu + ((u >> 16) & 1u);
  return (unsigned short)(u >> 16);
}

__device__ __forceinline__ void async16(void* lds, const void* g) {
  __builtin_amdgcn_global_load_lds(
      (const __attribute__((address_space(1))) void*)(uintptr_t)g,
      (__attribute__((address_space(3))) void*)(uint32_t)(uintptr_t)lds,
      16, 0, 0);
}

__device__ __forceinline__ bf16x8 ld8(const unsigned short* p) {
  return __builtin_bit_cast(bf16x8, *reinterpret_cast<const ushortx8*>(p));
}

// ---- fused prep: blocks [0,8192) convert A fp32->bf16; [8192,10240) build Ht
__global__ __launch_bounds__(256) void k_prep(const float* __restrict__ A,
                                              unsigned short* __restrict__ Ab,
                                              const float* __restrict__ W,
                                              unsigned short* __restrict__ Ht) {
  const int bid = blockIdx.x;
  if (bid < 8192) {
    const size_t t = (size_t)bid * 256 + threadIdx.x;
    const float4* a4 = reinterpret_cast<const float4*>(A);
    float4 v0 = a4[2 * t];
    float4 v1 = a4[2 * t + 1];
    ushortx8 o;
    o[0] = f2bf(v0.x); o[1] = f2bf(v0.y); o[2] = f2bf(v0.z); o[3] = f2bf(v0.w);
    o[4] = f2bf(v1.x); o[5] = f2bf(v1.y); o[6] = f2bf(v1.z); o[7] = f2bf(v1.w);
    *reinterpret_cast<ushortx8*>(Ab + t * 8) = o;
  } else {
    // Ht[b][a] = H_perm[a][b] = s(q,c) * W[u][(q^c)*512 + v]
    const int t = (bid - 8192) * 256 + threadIdx.x;
    const int b = t >> 8;
    const int a0 = (t & 255) << 3;
    const int c = b & 3, v = b >> 2;
    ushortx8 o;
#pragma unroll
    for (int e = 0; e < 8; ++e) {
      const int a = a0 + e;
      const int q = a & 3, u = a >> 2;
      float w = W[(size_t)u * OUT_F + ((q ^ c) << 9) + v];
      if ((0x284E >> ((q << 2) | c)) & 1) w = -w;
      o[e] = f2bf(w);
    }
    *reinterpret_cast<ushortx8*>(Ht + (size_t)b * IN_F + a0) = o;
  }
}

// ---- main GEMM: C = A(bf16) @ Ht^T + bias. 8-phase, raw-asm barriers. ----
__global__ __launch_bounds__(512, 2) void k_gemm(const unsigned short* __restrict__ A,
                                                 const unsigned short* __restrict__ Bt,
                                                 const float* __restrict__ bias,
                                                 float* __restrict__ C) {
  __shared__ __align__(16) unsigned short lds[2 * AB_STRIDE];  // 128 KiB

  const int tid = threadIdx.x;
  const int lane = tid & 63;
  const int w = tid >> 6;   // wave 0..7
  const int wm = w >> 2;    // 0..1 -> rows wm*128..+128
  const int wn = w & 3;     // 0..3 -> cols wn*64..+64
  const int fr = lane & 15;
  const int g = lane >> 4;  // k-subgroup 0..3

  // XCD-bijective swizzle: 256 wgs, 32 contiguous tiles per XCD
  const int wg = blockIdx.x;
  const int swz = (wg & 7) * (NWG >> 3) + (wg >> 3);
  const int tm = swz >> 3;
  const int tn = swz & 7;
  const int row0 = tm * BM, col0 = tn * BN;

  // ---- staging: half-tile = 128 rows x 64 k = 1024 x 16B chunks; thread tid
  // handles chunks tid and tid+512. chunk c: r=c>>3 (row), s=c&7 (16B slot).
  // T2 swizzle write side: slot s holds global k-group ga = s ^ (r&7)
  // (pre-swizzled GLOBAL source, linear LDS dest). r&7 == (tid>>3)&7 for both.
  const int kgsw = (((tid & 7) ^ ((tid >> 3) & 7)) << 3);
  const unsigned short* srcA0 = A + (size_t)(row0 + (tid >> 3)) * IN_F + kgsw;
  const unsigned short* srcB0 = Bt + (size_t)(col0 + (tid >> 3)) * IN_F + kgsw;

#define STG_A(P, H, T)                                                      \
  do {                                                                      \
    unsigned short* d_ = lds + (P) * AB_STRIDE + (H) * 8192 + tid * 8;      \
    const unsigned short* s_ = srcA0 + (size_t)(H) * 128 * IN_F + (T) * BK; \
    async16(d_, s_);                                                        \
    async16(d_ + 4096, s_ + (size_t)64 * IN_F);                             \
  } while (0)
#define STG_B(P, H, T)                                                        \
  do {                                                                        \
    unsigned short* d_ = lds + (P) * AB_STRIDE + B_OFF + (H) * 8192 + tid * 8;\
    const unsigned short* s_ = srcB0 + (size_t)(H) * 128 * IN_F + (T) * BK;   \
    async16(d_, s_);                                                          \
    async16(d_ + 4096, s_ + (size_t)64 * IN_F);                               \
  } while (0)

  // ---- fragment read offsets (shorts). row&7 == fr&7 for all frags.
  // slot for k-subgroup gk at row R: (gk ^ (R&7)); gk = g + 4*kh.
  int slot[2];
#pragma unroll
  for (int kh = 0; kh < 2; ++kh) slot[kh] = (((g + 4 * kh) ^ (fr & 7)) << 3);
  int offArow[8], offBrow[4];
#pragma unroll
  for (int m = 0; m < 8; ++m) offArow[m] = (wm * 128 + m * 16 + fr) * BK;
#pragma unroll
  for (int n = 0; n < 4; ++n) offBrow[n] = (wn * 64 + n * 16 + fr) * BK;

  f32x4 acc[8][4] = {};
  bf16x8 bF[4][2], aF[2][2];

#define MFMA_(a_, b_, c_) __builtin_amdgcn_mfma_f32_16x16x32_bf16(a_, b_, c_, 0, 0, 0)
#define FENCE_ __builtin_amdgcn_sched_barrier(0)
// raw-asm barrier: SIInsertWaitcnts can't attach a vmcnt(0) drain to it.
#define BAR_ asm volatile("s_barrier" ::: "memory")
#define LGKM0_ asm volatile("s_waitcnt lgkmcnt(0)" ::: "memory")
#define LGKM8_ asm volatile("s_waitcnt lgkmcnt(8)" ::: "memory")
#define VM4_ asm volatile("s_waitcnt vmcnt(4)" ::: "memory")
#define VM0_ asm volatile("s_waitcnt vmcnt(0)" ::: "memory")

#define RD_B(P)                                                               \
  _Pragma("unroll") for (int n = 0; n < 4; ++n)                               \
    _Pragma("unroll") for (int kh = 0; kh < 2; ++kh)                          \
      bF[n][kh] = ld8(lds + (P) * AB_STRIDE + B_OFF + offBrow[n] + slot[kh]);
#define RD_A(P, M0)                                                           \
  _Pragma("unroll") for (int e = 0; e < 2; ++e)                               \
    _Pragma("unroll") for (int kh = 0; kh < 2; ++kh)                          \
      aF[e][kh] = ld8(lds + (P) * AB_STRIDE + offArow[(M0) + e] + slot[kh]);
#define DO_MFMA(M0)                                                           \
  __builtin_amdgcn_s_setprio(1);                                              \
  _Pragma("unroll") for (int kh = 0; kh < 2; ++kh)                            \
    _Pragma("unroll") for (int n = 0; n < 4; ++n) {                           \
      acc[(M0)][n] = MFMA_(aF[0][kh], bF[n][kh], acc[(M0)][n]);               \
      acc[(M0) + 1][n] = MFMA_(aF[1][kh], bF[n][kh], acc[(M0) + 1][n]);       \
    }                                                                         \
  __builtin_amdgcn_s_setprio(0)

  // ---- prologue: land A(0),B(0) into S0 and B(1) into S1.B ----
  STG_A(0, 0, 0); STG_A(0, 1, 0);
  STG_B(0, 0, 0); STG_B(0, 1, 0);
  STG_B(1, 0, 1); STG_B(1, 1, 1);
  VM0_;
  BAR_; FENCE_;

  // ---- steady iterations i=0..14: ksteps 2i (S0), 2i+1 (S1).
  // Stage ledger: S1.A ph1-2 (A(2i+1)), S0.B ph3-4 (B(2i+2)),
  // S0.A ph5-6 (A(2i+2)), S1.B ph7-8 (B(2i+3)).
  // Outstanding sim (per thread, steady): iter-start 4 {B(2i+1)};
  // ph4 VM4 retires A(2i+1)+prior -> ph5 reads of B(2i+1),A(2i+1) safe;
  // ph8 VM4 retires B(2i+2),A(2i+2) -> next ph1 reads safe. Never drains 0.
#pragma unroll 1
  for (int i = 0; i < 15; ++i) {
    const int t1 = 2 * i + 1, t2 = 2 * i + 2, t3 = 2 * i + 3;
    // ph1 (12 reads)
    RD_B(0); RD_A(0, 0); FENCE_; STG_A(1, 0, t1); FENCE_; LGKM8_;
    BAR_; LGKM0_; FENCE_; DO_MFMA(0); FENCE_; BAR_; FENCE_;
    // ph2
    RD_A(0, 2); FENCE_; STG_A(1, 1, t1); FENCE_;
    BAR_; LGKM0_; FENCE_; DO_MFMA(2); FENCE_; BAR_; FENCE_;
    // ph3
    RD_A(0, 4); FENCE_; STG_B(0, 0, t2); FENCE_;
    BAR_; LGKM0_; FENCE_; DO_MFMA(4); FENCE_; BAR_; FENCE_;
    // ph4
    RD_A(0, 6); FENCE_; STG_B(0, 1, t2); FENCE_;
    BAR_; LGKM0_; FENCE_; DO_MFMA(6); FENCE_; VM4_; BAR_; FENCE_;
    // ph5 (12 reads)
    RD_B(1); RD_A(1, 0); FENCE_; STG_A(0, 0, t2); FENCE_; LGKM8_;
    BAR_; LGKM0_; FENCE_; DO_MFMA(0); FENCE_; BAR_; FENCE_;
    // ph6
    RD_A(1, 2); FENCE_; STG_A(0, 1, t2); FENCE_;
    BAR_; LGKM0_; FENCE_; DO_MFMA(2); FENCE_; BAR_; FENCE_;
    // ph7
    RD_A(1, 4); FENCE_; STG_B(1, 0, t3); FENCE_;
    BAR_; LGKM0_; FENCE_; DO_MFMA(4); FENCE_; BAR_; FENCE_;
    // ph8
    RD_A(1, 6); FENCE_; STG_B(1, 1, t3); FENCE_;
    BAR_; LGKM0_; FENCE_; DO_MFMA(6); FENCE_; VM4_; BAR_; FENCE_;
  }

  // ---- epilogue iteration (ksteps 30,31): only A(31) left to stage ----
  {
    // ph1
    RD_B(0); RD_A(0, 0); FENCE_; STG_A(1, 0, 31); FENCE_; LGKM8_;
    BAR_; LGKM0_; FENCE_; DO_MFMA(0); FENCE_; BAR_; FENCE_;
    // ph2
    RD_A(0, 2); FENCE_; STG_A(1, 1, 31); FENCE_;
    BAR_; LGKM0_; FENCE_; DO_MFMA(2); FENCE_; BAR_; FENCE_;
    // ph3
    RD_A(0, 4); FENCE_;
    BAR_; LGKM0_; FENCE_; DO_MFMA(4); FENCE_; BAR_; FENCE_;
    // ph4
    RD_A(0, 6); FENCE_;
    BAR_; LGKM0_; FENCE_; DO_MFMA(6); FENCE_; VM0_; BAR_; FENCE_;
    // ph5
    RD_B(1); RD_A(1, 0); FENCE_;
    BAR_; LGKM0_; FENCE_; DO_MFMA(0); FENCE_; BAR_; FENCE_;
    // ph6
    RD_A(1, 2); FENCE_;
    BAR_; LGKM0_; FENCE_; DO_MFMA(2); FENCE_; BAR_; FENCE_;
    // ph7
    RD_A(1, 4); FENCE_;
    BAR_; LGKM0_; FENCE_; DO_MFMA(4); FENCE_; BAR_; FENCE_;
    // ph8
    RD_A(1, 6); FENCE_;
    BAR_; LGKM0_; FENCE_; DO_MFMA(6); FENCE_;
  }

#undef RD_B
#undef RD_A
#undef DO_MFMA
#undef STG_A
#undef STG_B

  // ---- epilogue: C/D layout col=lane&15, row=(lane>>4)*4+reg ----
  const int g4 = g << 2;
  float bv[4];
#pragma unroll
  for (int n = 0; n < 4; ++n) bv[n] = bias[col0 + wn * 64 + n * 16 + fr];
#pragma unroll
  for (int m = 0; m < 8; ++m) {
#pragma unroll
    for (int e = 0; e < 4; ++e) {
      const int row = row0 + wm * 128 + m * 16 + g4 + e;
      float* cp = C + (size_t)row * OUT_F + col0 + wn * 64 + fr;
#pragma unroll
      for (int n = 0; n < 4; ++n) cp[n * 16] = acc[m][n][e] + bv[n];
    }
  }
}

// ---- fallback if workspace too small: naive fp32 ----
__global__ __launch_bounds__(256) void k_naive(const float* __restrict__ A,
                                               const float* __restrict__ W,
                                               const float* __restrict__ bias,
                                               float* __restrict__ C) {
  const int idx = blockIdx.x * 256 + threadIdx.x;
  const int m = idx >> 11;
  const int b = idx & (OUT_F - 1);
  const int c = b & 3, v = b >> 2;
  float acc = 0.f;
  const float* arow = A + (size_t)m * IN_F;
  for (int a = 0; a < IN_F; ++a) {
    const int q = a & 3, u = a >> 2;
    float h = W[(size_t)u * OUT_F + ((q ^ c) << 9) + v];
    if ((0x284E >> ((q << 2) | c)) & 1) h = -h;
    acc += arow[a] * h;
  }
  C[idx] = acc + bias[b];
}

extern "C" void kernel_launch(void* const* d_in, const int* in_sizes, int n_in,
                              void* d_out, int out_size, void* d_ws, size_t ws_size,
                              hipStream_t stream) {
  (void)in_sizes; (void)n_in; (void)out_size;
  const float* inp  = (const float*)d_in[0];
  const float* w    = (const float*)d_in[1];
  const float* bias = (const float*)d_in[2];
  float* out = (float*)d_out;

  const size_t needA = (size_t)N_ROWS * IN_F * sizeof(unsigned short);  // 32 MiB
  const size_t needH = (size_t)IN_F * OUT_F * sizeof(unsigned short);   //  8 MiB
  if (ws_size < needA + needH) {
    k_naive<<<(N_ROWS * OUT_F) / 256, 256, 0, stream>>>(inp, w, bias, out);
    return;
  }

  unsigned short* Ab = (unsigned short*)d_ws;
  unsigned short* Ht = Ab + (size_t)N_ROWS * IN_F;

  k_prep<<<8192 + 2048, 256, 0, stream>>>(inp, Ab, w, Ht);
  k_gemm<<<NWG, 512, 0, stream>>>(Ab, Ht, bias, out);
}